// Round 2
// baseline (6908.742 us; speedup 1.0000x reference)
//
#include <hip/hip_runtime.h>
#include <cstdint>
#include <cstddef>

#define H 1024
#define SEQ 512
#define THREEH 3072
#define VOCABN 32000
#define NBLK 64
#define HPB 16      // h-indices per block = H / NBLK
#define RPB 48      // rows per block = 3*HPB
#define RPW 12      // rows per wave = RPB / 4

// h is strictly in (-1,1); transport stores h+2 in (1,3). Any value <= 0.5
// (0xAA poison = -3e-13, NaN, zeros) means "not yet written".
#define HBIAS 2.0f
#define HVALID 0.5f

__device__ __forceinline__ float wave_sum(float v) {
    v += __shfl_xor(v, 32);
    v += __shfl_xor(v, 16);
    v += __shfl_xor(v, 8);
    v += __shfl_xor(v, 4);
    v += __shfl_xor(v, 2);
    v += __shfl_xor(v, 1);
    return v;
}

// Persistent recurrent kernel: 64 blocks, each owns 16 h-indices (48 rows of
// Whh in VGPRs). Cross-block exchange: data-as-flag. Producer stores biased
// h (agent scope, relaxed); consumers poll the values they need directly
// into registers. No flags, no global barrier, no LDS h-staging.
__global__ __launch_bounds__(256, 1) void rnn_persistent(
    const float* __restrict__ eWhh, const float* __restrict__ ebhh,
    const float* __restrict__ dWhh, const float* __restrict__ dbhh,
    const float* __restrict__ gxe, const float* __restrict__ gxd,
    float* __restrict__ enc_t,     // [SEQ][H] biased transport (enc)
    float* __restrict__ dec_t,     // [SEQ][H] biased transport (dec)
    float* __restrict__ dec_hs)    // [SEQ][H] raw h for projection
{
    const int tid = threadIdx.x;
    const int blk = blockIdx.x;
    const int wave = tid >> 6;
    const int lane = tid & 63;
    const int i0 = blk * HPB;

    __shared__ float ghs[RPB];
    __shared__ float bhs[RPB];
    __shared__ float ownh[HPB];   // this block's h slice from previous step

    float4 wreg[RPW][4];

    auto load_w = [&](const float* __restrict__ W, const float* __restrict__ bhh) {
        __syncthreads();   // entry: wave0's gates of prev step must finish bhs reads
#pragma unroll
        for (int j = 0; j < RPW; ++j) {
            int lr = wave * RPW + j;
            int g = lr / HPB, jj = lr % HPB;
            const float* base = W + (size_t)(g * H + i0 + jj) * H + lane * 4;
#pragma unroll
            for (int m = 0; m < 4; ++m)
                wreg[j][m] = *(const float4*)(base + 256 * m);
        }
        if (tid < RPB) {
            int g = tid / HPB, jj = tid % HPB;
            bhs[tid] = bhh[g * H + i0 + jj];
        }
        __syncthreads();
    };

    if (tid < HPB) ownh[tid] = 0.f;
    load_w(eWhh, ebhh);

    for (unsigned step = 0; step < 2 * SEQ; ++step) {
        const bool dec = step >= SEQ;
        const int t = dec ? (int)(step - SEQ) : (int)step;
        if (dec && t == 0) load_w(dWhh, dbhh);

        const float* gx = dec ? gxd : gxe;
        // transport buffer holding h produced at step-1 (unique per step)
        const float* tb_prev =
            (step == 0) ? nullptr
                        : (step <= SEQ ? enc_t + (size_t)(step - 1) * H
                                       : dec_t + (size_t)(step - SEQ - 1) * H);
        float* tb_out = dec ? dec_t + (size_t)t * H : enc_t + (size_t)t * H;

        // prefetch gx for gate threads (independent, issues early)
        float gxr = 0.f, gxz = 0.f, gxn = 0.f;
        if (tid < HPB) {
            const float* g = gx + (size_t)t * THREEH;
            gxr = g[i0 + tid];
            gxz = g[H + i0 + tid];
            gxn = g[2 * H + i0 + tid];
        }

        // poll the 16 h values this thread needs for the matvec
        float hv[16];
        if (tb_prev) {
            const unsigned long long* src = (const unsigned long long*)tb_prev;
            unsigned mask = 0;
            while (mask != 0xFFu) {
#pragma unroll
                for (int m = 0; m < 4; ++m) {
#pragma unroll
                    for (int q = 0; q < 2; ++q) {
                        const unsigned b = (unsigned)(m * 2 + q);
                        if (mask & (1u << b)) continue;
                        unsigned long long v = __hip_atomic_load(
                            src + lane * 2 + 128 * m + q,
                            __ATOMIC_RELAXED, __HIP_MEMORY_SCOPE_AGENT);
                        union { unsigned long long u; float f[2]; } cv;
                        cv.u = v;
                        if (cv.f[0] > HVALID && cv.f[1] > HVALID) {
                            hv[m * 4 + q * 2]     = cv.f[0] - HBIAS;
                            hv[m * 4 + q * 2 + 1] = cv.f[1] - HBIAS;
                            mask |= 1u << b;
                        }
                    }
                }
            }
        } else {
#pragma unroll
            for (int k = 0; k < 16; ++k) hv[k] = 0.f;
        }

        // matvec: 12 rows/wave against this thread's 16 h values
#pragma unroll
        for (int j = 0; j < RPW; ++j) {
            float acc = 0.f;
#pragma unroll
            for (int m = 0; m < 4; ++m) {
                float4 w = wreg[j][m];
                acc += w.x * hv[m * 4 + 0] + w.y * hv[m * 4 + 1]
                     + w.z * hv[m * 4 + 2] + w.w * hv[m * 4 + 3];
            }
            acc = wave_sum(acc);
            if (lane == 0) ghs[wave * RPW + j] = acc;
        }
        __syncthreads();   // ghs produced (all waves) -> consumed (wave 0)

        if (tid < HPB) {
            float hvp = ownh[tid];
            float ghr = ghs[tid] + bhs[tid];
            float ghz = ghs[HPB + tid] + bhs[HPB + tid];
            float ghn = ghs[2 * HPB + tid] + bhs[2 * HPB + tid];
            float r = 1.f / (1.f + expf(-(gxr + ghr)));
            float z = 1.f / (1.f + expf(-(gxz + ghz)));
            float n = tanhf(gxn + r * ghn);
            float hnew = (1.f - z) * n + z * hvp;
            ownh[tid] = hnew;
            __hip_atomic_store(tb_out + i0 + tid, hnew + HBIAS,
                               __ATOMIC_RELAXED, __HIP_MEMORY_SCOPE_AGENT);
            if (dec) dec_hs[(size_t)t * H + i0 + tid] = hnew;
        }
        // no trailing barrier: waves 1-3 can only pass poll(step+1) after
        // wave 0's stores above, which are after wave 0's ghs/bhs reads.
    }
}

// Tiled fp32 GEMM, C[m][n] = dot(Arow(m), W[n]) + bias[n].
// mode 0: Arow = Abase[inputs[m]]   (encoder embedding gather)
// mode 1: Arow = Abase[m==0 ? 0 : targets[m-1]] (decoder teacher forcing)
// mode 2: Arow = Abase[m]           (projection from dec_hs)
__global__ __launch_bounds__(256, 2) void gemm_nt(
    const float* __restrict__ Abase,
    const int* __restrict__ toks0,
    const int* __restrict__ toks1,
    const int mode,
    const float* __restrict__ W,
    const float* __restrict__ bias,
    float* __restrict__ C, const int N)
{
    constexpr int TM = 64, TN = 64, TK = 16;
    __shared__ float As[TK][TM + 4];
    __shared__ float Bs[TK][TN + 4];
    const int tid = threadIdx.x;
    const int n0 = blockIdx.x * TN;
    const int m0 = blockIdx.y * TM;
    const int r = tid >> 2;
    const int c = tid & 3;
    const int tx = tid & 15;
    const int ty = tid >> 4;

    const int m = m0 + r;
    const float* Arow;
    if (mode == 0)      Arow = Abase + (size_t)toks0[m] * H;
    else if (mode == 1) Arow = Abase + (size_t)(m == 0 ? 0 : toks1[m - 1]) * H;
    else                Arow = Abase + (size_t)m * H;
    const float* Brow = W + (size_t)(n0 + r) * H;

    float acc[4][4] = {};

    for (int k0 = 0; k0 < H; k0 += TK) {
        float4 av = *(const float4*)(Arow + k0 + c * 4);
        float4 bv = *(const float4*)(Brow + k0 + c * 4);
        __syncthreads();
        As[c * 4 + 0][r] = av.x; As[c * 4 + 1][r] = av.y;
        As[c * 4 + 2][r] = av.z; As[c * 4 + 3][r] = av.w;
        Bs[c * 4 + 0][r] = bv.x; Bs[c * 4 + 1][r] = bv.y;
        Bs[c * 4 + 2][r] = bv.z; Bs[c * 4 + 3][r] = bv.w;
        __syncthreads();
#pragma unroll
        for (int kk = 0; kk < TK; ++kk) {
            float4 a = *(const float4*)&As[kk][ty * 4];
            float4 b = *(const float4*)&Bs[kk][tx * 4];
            float avv[4] = {a.x, a.y, a.z, a.w};
            float bvv[4] = {b.x, b.y, b.z, b.w};
#pragma unroll
            for (int i = 0; i < 4; ++i)
#pragma unroll
                for (int j = 0; j < 4; ++j)
                    acc[i][j] += avv[i] * bvv[j];
        }
    }

    float4 bq = *(const float4*)(bias + n0 + tx * 4);
    float bb[4] = {bq.x, bq.y, bq.z, bq.w};
#pragma unroll
    for (int i = 0; i < 4; ++i) {
        float4 o;
        o.x = acc[i][0] + bb[0];
        o.y = acc[i][1] + bb[1];
        o.z = acc[i][2] + bb[2];
        o.w = acc[i][3] + bb[3];
        *(float4*)&C[(size_t)(m0 + ty * 4 + i) * N + n0 + tx * 4] = o;
    }
}

extern "C" void kernel_launch(void* const* d_in, const int* in_sizes, int n_in,
                              void* d_out, int out_size, void* d_ws, size_t ws_size,
                              hipStream_t stream) {
    const int*   inputs  = (const int*)d_in[0];
    const int*   targets = (const int*)d_in[1];
    const float* emb     = (const float*)d_in[2];
    const float* eWih    = (const float*)d_in[3];
    const float* eWhh    = (const float*)d_in[4];
    const float* ebih    = (const float*)d_in[5];
    const float* ebhh    = (const float*)d_in[6];
    const float* dWih    = (const float*)d_in[7];
    const float* dWhh    = (const float*)d_in[8];
    const float* dbih    = (const float*)d_in[9];
    const float* dbhh    = (const float*)d_in[10];
    const float* pW      = (const float*)d_in[11];
    const float* pb      = (const float*)d_in[12];
    float* out = (float*)d_out;

    float* gxe    = (float*)d_ws;                  // [512][3072]
    float* gxd    = gxe + (size_t)SEQ * THREEH;    // [512][3072]
    float* enc_t  = gxd + (size_t)SEQ * THREEH;    // [512][1024] biased
    float* dec_t  = enc_t + (size_t)SEQ * H;       // [512][1024] biased
    float* dec_hs = dec_t + (size_t)SEQ * H;       // [512][1024] raw

    // input-side GEMMs: gx = Wih @ emb[tok] + bih
    gemm_nt<<<dim3(THREEH / 64, SEQ / 64), 256, 0, stream>>>(
        emb, inputs, targets, 0, eWih, ebih, gxe, THREEH);
    gemm_nt<<<dim3(THREEH / 64, SEQ / 64), 256, 0, stream>>>(
        emb, inputs, targets, 1, dWih, dbih, gxd, THREEH);

    // sequential recurrence (enc 512 steps then dec 512 steps),
    // self-synchronizing via data-as-flag transport buffers
    rnn_persistent<<<NBLK, 256, 0, stream>>>(
        eWhh, ebhh, dWhh, dbhh, gxe, gxd, enc_t, dec_t, dec_hs);

    // projection: logits = dec_hs @ proj_W^T + proj_b
    gemm_nt<<<dim3(VOCABN / 64, SEQ / 64), 256, 0, stream>>>(
        dec_hs, nullptr, nullptr, 2, pW, pb, out, VOCABN);
}

// Round 3
// 5089.257 us; speedup vs baseline: 1.3575x; 1.3575x over previous
//
#include <hip/hip_runtime.h>
#include <cstdint>
#include <cstddef>

#define H 1024
#define SEQ 512
#define THREEH 3072
#define VOCABN 32000
#define NBLK 64
#define HPB 16      // h-indices per block = H / NBLK
#define RPW 12      // rows per wave = 3 gates x 4 indices

// h strictly in (-1,1); transport stores h+2 in (1,3). Anything <= 0.5
// (0xAA poison = -3e-13, NaN, zeros) means "not yet written".
#define HBIAS 2.0f
#define HVALID 0.5f

__device__ __forceinline__ float wave_sum(float v) {
    v += __shfl_xor(v, 32);
    v += __shfl_xor(v, 16);
    v += __shfl_xor(v, 8);
    v += __shfl_xor(v, 4);
    v += __shfl_xor(v, 2);
    v += __shfl_xor(v, 1);
    return v;
}

// Persistent recurrent kernel: 64 blocks (1/CU), each owns 16 h-indices.
// Wave w owns the r,z,n rows of h-indices i0+4w..i0+4w+3 (12 rows, in regs).
// Only wave 0 polls the LLC transport (data-as-flag); h is distributed
// intra-block through double-buffered LDS with ONE barrier per step.
// Gates are computed in-register from the broadcast wave_sum results.
__global__ __launch_bounds__(256, 1) void rnn_persistent(
    const float* __restrict__ eWhh, const float* __restrict__ ebhh,
    const float* __restrict__ dWhh, const float* __restrict__ dbhh,
    const float* __restrict__ gxe, const float* __restrict__ gxd,
    float* __restrict__ enc_t,     // [SEQ][H] biased transport (enc)
    float* __restrict__ dec_t)     // [SEQ][H] biased transport (dec)
{
    const int tid = threadIdx.x;
    const int blk = blockIdx.x;
    const int wave = tid >> 6;
    const int lane = tid & 63;
    const int i0 = blk * HPB;
    const int j = lane & 3;
    const int myidx = i0 + 4 * wave + j;   // h-index this lane's gates cover

    __shared__ float hs[2][H];

    float4 wreg[RPW][4];   // wreg[g*4+jj][m] = W[g*H + i0+4*wave+jj][lane*4+256m ..]
    float br, bz, bn;
    float hown = 0.f;

    auto load_w = [&](const float* __restrict__ W, const float* __restrict__ b) {
#pragma unroll
        for (int lr = 0; lr < RPW; ++lr) {
            const int g = lr >> 2, jj = lr & 3;
            const float* base =
                W + (size_t)(g * H + i0 + 4 * wave + jj) * H + lane * 4;
#pragma unroll
            for (int m = 0; m < 4; ++m)
                wreg[lr][m] = *(const float4*)(base + 256 * m);
        }
        br = b[myidx];
        bz = b[H + myidx];
        bn = b[2 * H + myidx];
    };

    load_w(eWhh, ebhh);

    for (int step = 0; step < 2 * SEQ; ++step) {
        const bool dec = step >= SEQ;
        const int t = dec ? step - SEQ : step;
        if (dec && t == 0) load_w(dWhh, dbhh);

        const float* gx = dec ? gxd : gxe;
        float* tb_out = (dec ? dec_t : enc_t) + (size_t)t * H;
        const int buf = step & 1;

        // gx prefetch (plain cached loads, independent of the poll)
        const float* gxp = gx + (size_t)t * THREEH + myidx;
        float gxr = gxp[0];
        float gxz = gxp[H];
        float gxn = gxp[2 * H];

        if (wave == 0) {
            if (step == 0) {
#pragma unroll
                for (int m = 0; m < 4; ++m)
                    *(float4*)&hs[buf][lane * 4 + 256 * m] = float4{0.f, 0.f, 0.f, 0.f};
            } else {
                const float* tb_prev =
                    (step <= SEQ) ? enc_t + (size_t)(step - 1) * H
                                  : dec_t + (size_t)(step - SEQ - 1) * H;
                const unsigned long long* src = (const unsigned long long*)tb_prev;
                union { unsigned long long u; float f[2]; } cv[8];
                for (;;) {
#pragma unroll
                    for (int m = 0; m < 4; ++m)
#pragma unroll
                        for (int q = 0; q < 2; ++q)
                            cv[m * 2 + q].u = __hip_atomic_load(
                                src + lane * 2 + 128 * m + q,
                                __ATOMIC_RELAXED, __HIP_MEMORY_SCOPE_AGENT);
                    bool ok = true;
#pragma unroll
                    for (int k = 0; k < 8; ++k)
                        ok &= (cv[k].f[0] > HVALID) & (cv[k].f[1] > HVALID);
                    if (ok) break;
                    __builtin_amdgcn_s_sleep(1);   // backoff: unload hot lines
                }
#pragma unroll
                for (int m = 0; m < 4; ++m) {
                    float4 v;
                    v.x = cv[m * 2 + 0].f[0] - HBIAS;
                    v.y = cv[m * 2 + 0].f[1] - HBIAS;
                    v.z = cv[m * 2 + 1].f[0] - HBIAS;
                    v.w = cv[m * 2 + 1].f[1] - HBIAS;
                    *(float4*)&hs[buf][lane * 4 + 256 * m] = v;
                }
            }
        }
        __syncthreads();   // the ONLY barrier per step

        float4 hv4[4];
#pragma unroll
        for (int m = 0; m < 4; ++m)
            hv4[m] = *(const float4*)&hs[buf][lane * 4 + 256 * m];

        float sums[RPW];
#pragma unroll
        for (int lr = 0; lr < RPW; ++lr) {
            float acc = 0.f;
#pragma unroll
            for (int m = 0; m < 4; ++m) {
                float4 w = wreg[lr][m], h = hv4[m];
                acc += w.x * h.x + w.y * h.y + w.z * h.z + w.w * h.w;
            }
            sums[lr] = wave_sum(acc);   // broadcast to all lanes
        }

        // per-lane gate-row selection (j = lane & 3), all in registers
        float sr = (j == 0) ? sums[0] : (j == 1) ? sums[1] : (j == 2) ? sums[2] : sums[3];
        float sz = (j == 0) ? sums[4] : (j == 1) ? sums[5] : (j == 2) ? sums[6] : sums[7];
        float sn = (j == 0) ? sums[8] : (j == 1) ? sums[9] : (j == 2) ? sums[10] : sums[11];

        float rg = 1.f / (1.f + expf(-(gxr + sr + br)));
        float zg = 1.f / (1.f + expf(-(gxz + sz + bz)));
        float ng = tanhf(gxn + rg * (sn + bn));
        float hnew = (1.f - zg) * ng + zg * hown;
        hown = hnew;

        if (lane < 4)
            __hip_atomic_store(tb_out + i0 + 4 * wave + lane, hnew + HBIAS,
                               __ATOMIC_RELAXED, __HIP_MEMORY_SCOPE_AGENT);
    }
}

// Tiled fp32 GEMM, C[m][n] = dot(Arow(m), W[n]) + bias[n].
// mode 0: Arow = Abase[inputs[m]]   (encoder embedding gather)
// mode 1: Arow = Abase[m==0 ? 0 : targets[m-1]] (decoder teacher forcing)
// mode 2: Arow = Abase[m] - HBIAS   (projection from biased dec transport)
__global__ __launch_bounds__(256, 2) void gemm_nt(
    const float* __restrict__ Abase,
    const int* __restrict__ toks0,
    const int* __restrict__ toks1,
    const int mode,
    const float* __restrict__ W,
    const float* __restrict__ bias,
    float* __restrict__ C, const int N)
{
    constexpr int TM = 64, TN = 64, TK = 16;
    __shared__ float As[TK][TM + 4];
    __shared__ float Bs[TK][TN + 4];
    const int tid = threadIdx.x;
    const int n0 = blockIdx.x * TN;
    const int m0 = blockIdx.y * TM;
    const int r = tid >> 2;
    const int c = tid & 3;
    const int tx = tid & 15;
    const int ty = tid >> 4;

    const int m = m0 + r;
    const float* Arow;
    if (mode == 0)      Arow = Abase + (size_t)toks0[m] * H;
    else if (mode == 1) Arow = Abase + (size_t)(m == 0 ? 0 : toks1[m - 1]) * H;
    else                Arow = Abase + (size_t)m * H;
    const float* Brow = W + (size_t)(n0 + r) * H;
    const float abias = (mode == 2) ? HBIAS : 0.f;

    float acc[4][4] = {};

    for (int k0 = 0; k0 < H; k0 += TK) {
        float4 av = *(const float4*)(Arow + k0 + c * 4);
        float4 bv = *(const float4*)(Brow + k0 + c * 4);
        __syncthreads();
        As[c * 4 + 0][r] = av.x - abias; As[c * 4 + 1][r] = av.y - abias;
        As[c * 4 + 2][r] = av.z - abias; As[c * 4 + 3][r] = av.w - abias;
        Bs[c * 4 + 0][r] = bv.x; Bs[c * 4 + 1][r] = bv.y;
        Bs[c * 4 + 2][r] = bv.z; Bs[c * 4 + 3][r] = bv.w;
        __syncthreads();
#pragma unroll
        for (int kk = 0; kk < TK; ++kk) {
            float4 a = *(const float4*)&As[kk][ty * 4];
            float4 b = *(const float4*)&Bs[kk][tx * 4];
            float avv[4] = {a.x, a.y, a.z, a.w};
            float bvv[4] = {b.x, b.y, b.z, b.w};
#pragma unroll
            for (int i = 0; i < 4; ++i)
#pragma unroll
                for (int jj = 0; jj < 4; ++jj)
                    acc[i][jj] += avv[i] * bvv[jj];
        }
    }

    float4 bq = *(const float4*)(bias + n0 + tx * 4);
    float bb[4] = {bq.x, bq.y, bq.z, bq.w};
#pragma unroll
    for (int i = 0; i < 4; ++i) {
        float4 o;
        o.x = acc[i][0] + bb[0];
        o.y = acc[i][1] + bb[1];
        o.z = acc[i][2] + bb[2];
        o.w = acc[i][3] + bb[3];
        *(float4*)&C[(size_t)(m0 + ty * 4 + i) * N + n0 + tx * 4] = o;
    }
}

extern "C" void kernel_launch(void* const* d_in, const int* in_sizes, int n_in,
                              void* d_out, int out_size, void* d_ws, size_t ws_size,
                              hipStream_t stream) {
    const int*   inputs  = (const int*)d_in[0];
    const int*   targets = (const int*)d_in[1];
    const float* emb     = (const float*)d_in[2];
    const float* eWih    = (const float*)d_in[3];
    const float* eWhh    = (const float*)d_in[4];
    const float* ebih    = (const float*)d_in[5];
    const float* ebhh    = (const float*)d_in[6];
    const float* dWih    = (const float*)d_in[7];
    const float* dWhh    = (const float*)d_in[8];
    const float* dbih    = (const float*)d_in[9];
    const float* dbhh    = (const float*)d_in[10];
    const float* pW      = (const float*)d_in[11];
    const float* pb      = (const float*)d_in[12];
    float* out = (float*)d_out;

    float* gxe   = (float*)d_ws;                  // [512][3072]
    float* gxd   = gxe + (size_t)SEQ * THREEH;    // [512][3072]
    float* enc_t = gxd + (size_t)SEQ * THREEH;    // [512][1024] biased
    float* dec_t = enc_t + (size_t)SEQ * H;       // [512][1024] biased

    // input-side GEMMs: gx = Wih @ emb[tok] + bih
    gemm_nt<<<dim3(THREEH / 64, SEQ / 64), 256, 0, stream>>>(
        emb, inputs, targets, 0, eWih, ebih, gxe, THREEH);
    gemm_nt<<<dim3(THREEH / 64, SEQ / 64), 256, 0, stream>>>(
        emb, inputs, targets, 1, dWih, dbih, gxd, THREEH);

    // sequential recurrence (enc 512 steps then dec 512 steps),
    // self-synchronizing via data-as-flag transport buffers
    rnn_persistent<<<NBLK, 256, 0, stream>>>(
        eWhh, ebhh, dWhh, dbhh, gxe, gxd, enc_t, dec_t);

    // projection: logits = (dec_t - HBIAS) @ proj_W^T + proj_b
    gemm_nt<<<dim3(VOCABN / 64, SEQ / 64), 256, 0, stream>>>(
        dec_t, nullptr, nullptr, 2, pW, pb, out, VOCABN);
}